// Round 6
// baseline (29.393 us; speedup 1.0000x reference)
//
#include <hip/hip_runtime.h>

// Scalar VQ (dim=1, K=64) via per-block bucket LUT, depth-1 LDS chain.
// key(x)=clamp((x-lo)*inv,0,NB-1) is fl-monotone; build uses the SAME key on
// the sorted codes, so for key(w)=k with <=2 codes in bucket k:
//   pos(w) = #{c<=w} = p0(k) + (S[p0+1]<=w) + (S[p0+2]<=w)   (exact)
// Candidates S[pos],S[pos+1] compared with exact reference arithmetic
// (d=fl(w-c), d2=fl(d*d)); >=3-code buckets are NaN-marked; those, exact
// fl-ties between distinct values, and non-finite w fall back to the verbatim
// naive first-index scan under a __any guard (~never taken).
// R6: build amortized (512 blocks = 2/CU, 16384 elems/block) + chunked
// prefetch for memory-latency hiding. Hot path unchanged from R5 (absmax 0).

#define VQ_K 64
#define NB   1024
#define NW   (NB / 4)          // byte-packed histogram words (== TPB)
#define TPB  256
#define SEG  16                // float4 segments per thread
#define CHUNK 4                // float4 in flight per prefetch step
#define BLK_F4 (TPB * SEG)     // 4096 float4 = 16384 floats per block

__device__ __forceinline__ int vq_key(float x, float lo, float inv) {
    float t = (x - lo) * inv;
    t = fminf(fmaxf(t, 0.0f), (float)(NB - 1));
    return (int)t;
}

__device__ __forceinline__ unsigned bytesum(unsigned x) {
    return (x + (x >> 8) + (x >> 16) + (x >> 24)) & 0xFFu;
}

__global__ __launch_bounds__(TPB, 2) void vq_kernel(
    const float* __restrict__ w,
    const float* __restrict__ cb,
    float* __restrict__ out,
    int n4)
{
    __shared__ float  C[VQ_K];        // original order (fallback)
    __shared__ float  S[VQ_K + 4];    // [0]=inf, [1..64] sorted, [65..67]=inf
    __shared__ float4 T[NB];          // 16 KB bucket table
    __shared__ unsigned H[NW];        // byte-packed counts
    __shared__ unsigned Hs[NW];       // word-exclusive code prefix

    const int tid = threadIdx.x;
    const float INF = __builtin_inff();
    const float NANF = __uint_as_float(0x7fc00000u);

    if (tid < VQ_K) C[tid] = cb[tid];
    H[tid] = 0u;                       // NW == TPB
    __syncthreads();

    // Stable rank-sort into S[1..64].
    if (tid < VQ_K) {
        const float c = C[tid];
        int rank = 0;
#pragma unroll
        for (int j = 0; j < VQ_K; ++j) {
            const float cj = C[j];
            rank += (cj < c || (cj == c && j < tid)) ? 1 : 0;
        }
        S[rank + 1] = c;
    }
    if (tid == 0) S[0] = INF;
    if (tid >= VQ_K + 1 && tid <= VQ_K + 3) S[tid] = INF;
    __syncthreads();

    const float lo  = S[1];
    const float hi  = S[VQ_K];
    const float inv = (hi > lo) ? ((float)NB / (hi - lo)) : 0.0f;

    if (tid < VQ_K) {
        const int k = vq_key(S[tid + 1], lo, inv);
        atomicAdd(&H[k >> 2], 1u << ((k & 3) * 8));
    }
    __syncthreads();

    // Wave 0: exclusive scan over 256 words (4 words/lane + shfl scan).
    if (tid < 64) {
        const unsigned w0 = H[4 * tid], w1 = H[4 * tid + 1];
        const unsigned w2 = H[4 * tid + 2], w3 = H[4 * tid + 3];
        const int s0 = (int)bytesum(w0), s1 = (int)bytesum(w1);
        const int s2 = (int)bytesum(w2), s3 = (int)bytesum(w3);
        const int tot = s0 + s1 + s2 + s3;
        int acc = tot;
#pragma unroll
        for (int d = 1; d < 64; d <<= 1) {
            int u = __shfl_up(acc, d, 64);
            if ((tid & 63) >= d) acc += u;
        }
        const int base = acc - tot;
        Hs[4 * tid]     = (unsigned)base;
        Hs[4 * tid + 1] = (unsigned)(base + s0);
        Hs[4 * tid + 2] = (unsigned)(base + s0 + s1);
        Hs[4 * tid + 3] = (unsigned)(base + s0 + s1 + s2);
    }
    __syncthreads();

    // Fill T: thread t owns buckets {t, 256+t, 512+t, 768+t} -> lane-consecutive
    // 16B writes (conflict-free b128).
#pragma unroll
    for (int j = 0; j < 4; ++j) {
        const int b = tid + j * TPB;
        const unsigned hw = H[b >> 2];
        const int sh = (b & 3) * 8;
        const int h = (int)((hw >> sh) & 0xFFu);
        const unsigned below = hw & ((sh == 0) ? 0u : ((1u << sh) - 1u));
        const int p0 = (int)Hs[b >> 2] + (int)bytesum(below);
        float4 ent;
        if (h >= 3) ent = make_float4(NANF, NANF, NANF, NANF);
        else        ent = make_float4(S[p0], S[p0 + 1], S[p0 + 2], S[p0 + 3]);
        T[b] = ent;
    }
    __syncthreads();

    // ---- stream SEG float4 per thread, chunked with prefetch ----
    const int base4 = blockIdx.x * BLK_F4 + tid;   // full blocks only
    const float4* in4 = reinterpret_cast<const float4*>(w);
    float4* out4 = reinterpret_cast<float4*>(out);

    float4 cur[CHUNK];
#pragma unroll
    for (int c = 0; c < CHUNK; ++c) cur[c] = in4[base4 + c * TPB];

#pragma unroll
    for (int cs = 0; cs < SEG; cs += CHUNK) {
        float4 nxt[CHUNK];
        const bool more = (cs + CHUNK < SEG);
        if (more) {
#pragma unroll
            for (int c = 0; c < CHUNK; ++c)
                nxt[c] = in4[base4 + (cs + CHUNK + c) * TPB];
        }
#pragma unroll
        for (int c = 0; c < CHUNK; ++c) {
            const float4 x = cur[c];
            float ex[4] = {x.x, x.y, x.z, x.w};
            float r[4];
#pragma unroll
            for (int j = 0; j < 4; ++j) {
                const float wv = ex[j];
                const int k = vq_key(wv, lo, inv);
                const float4 ent = T[k];              // one ds_read_b128
                const bool s1 = (ent.y <= wv);
                const bool s2 = (ent.z <= wv);
                const float cl = s2 ? ent.z : (s1 ? ent.y : ent.x);
                const float cr = s2 ? ent.w : (s1 ? ent.z : ent.y);
                const float dl = wv - cl, dr = wv - cr;
                const float dl2 = dl * dl, dr2 = dr * dr;
                float q = (dr2 < dl2) ? cr : cl;
                const bool bad = (q != q) || (dl2 == dr2 && cl != cr)
                                 || !((wv - wv) == 0.0f);
                if (__any(bad)) {                     // uniform, ~never taken
                    if (bad) {
                        float c0 = C[0], d0 = wv - c0;
                        float bd = d0 * d0, bv = c0;
#pragma unroll 1
                        for (int kk = 1; kk < VQ_K; ++kk) {
                            float cc = C[kk], d = wv - cc, dd = d * d;
                            bool lt = dd < bd;
                            bd = lt ? dd : bd;
                            bv = lt ? cc : bv;
                        }
                        q = bv;
                    }
                }
                r[j] = q;
            }
            out4[base4 + (cs + c) * TPB] = make_float4(r[0], r[1], r[2], r[3]);
        }
        if (more) {
#pragma unroll
            for (int c = 0; c < CHUNK; ++c) cur[c] = nxt[c];
        }
    }
}

// Naive exact fallback for any remainder elements.
__global__ void vq_tail_kernel(const float* __restrict__ w,
                               const float* __restrict__ cb,
                               float* __restrict__ out, int start, int n) {
    int i = start + blockIdx.x * blockDim.x + threadIdx.x;
    if (i >= n) return;
    float wx = w[i];
    float c0 = cb[0], d0 = wx - c0;
    float bd = d0 * d0, bv = c0;
#pragma unroll
    for (int k = 1; k < VQ_K; ++k) {
        float c = cb[k], d = wx - c, dd = d * d;
        bool lt = dd < bd;
        bd = lt ? dd : bd;
        bv = lt ? c : bv;
    }
    out[i] = bv;
}

extern "C" void kernel_launch(void* const* d_in, const int* in_sizes, int n_in,
                              void* d_out, int out_size, void* d_ws, size_t ws_size,
                              hipStream_t stream) {
    const float* w  = (const float*)d_in[0];
    const float* cb = (const float*)d_in[1];
    float* out = (float*)d_out;
    const int n  = in_sizes[0];
    const int n4 = n / 4;

    const int grid = n4 / BLK_F4;                 // full blocks only
    if (grid > 0) {
        vq_kernel<<<grid, TPB, 0, stream>>>(w, cb, out, n4);
    }
    const int done = grid * BLK_F4 * 4;
    if (done < n) {
        const int rem = n - done;
        vq_tail_kernel<<<(rem + TPB - 1) / TPB, TPB, 0, stream>>>(w, cb, out, done, n);
    }
}

// Round 7
// 26.641 us; speedup vs baseline: 1.1033x; 1.1033x over previous
//
#include <hip/hip_runtime.h>

// Scalar VQ (dim=1, K=64) via per-block bucket LUT, depth-1 LDS chain.
// key(x)=trunc(clamp(fmaf(x,inv,nlo),0,NB-1)) is fl-monotone; build uses the
// SAME key (same inv,nlo registers) on the sorted codes, so for key(w)=k with
// <=2 codes in bucket k:
//   pos(w) = #{c<=w} = p0(k) + (S[p0+1]<=w) + (S[p0+2]<=w)   (exact)
// Candidates S[pos],S[pos+1] compared with exact reference arithmetic
// (d=fl(w-c), d2=fl(d*d)); >=3-code buckets NaN-marked; those, exact fl-ties
// between distinct values, and non-finite w hit the verbatim naive first-index
// scan under a __any guard (~never taken).
// R7: occupancy pinned — TPB=1024, __launch_bounds__(1024,8) => 2 blocks/CU =
// 32 waves/CU, VGPR<=64; SEG=2 keeps live state small; build 4x/CU shared by
// 16 waves. Hot path leaner (fmaf+med3 key, 3-compare guard).

#define VQ_K 64
#define NB   1024
#define NW   (NB / 4)
#define TPB  1024
#define SEG  2
#define BLK_F4 (TPB * SEG)     // 2048 float4 = 8192 floats per block

__device__ __forceinline__ unsigned bytesum(unsigned x) {
    return (x + (x >> 8) + (x >> 16) + (x >> 24)) & 0xFFu;
}

__device__ __forceinline__ int vq_key(float x, float inv, float nlo) {
    float t = fmaf(x, inv, nlo);                      // monotone in x (inv>=0)
    t = fminf(fmaxf(t, 0.0f), (float)(NB - 1));       // v_med3_f32
    return (int)t;
}

__global__ __launch_bounds__(TPB, 8) void vq_kernel(
    const float* __restrict__ w,
    const float* __restrict__ cb,
    float* __restrict__ out,
    int n4)
{
    __shared__ float  C[VQ_K];        // original order (fallback)
    __shared__ float  S[VQ_K + 4];    // [0]=inf, [1..64] sorted, [65..67]=inf
    __shared__ float4 T[NB];          // 16 KB bucket table
    __shared__ unsigned H[NW];        // byte-packed counts
    __shared__ unsigned Hs[NW];       // word-exclusive code prefix

    const int tid = threadIdx.x;
    const float INF = __builtin_inff();
    const float NANF = __uint_as_float(0x7fc00000u);

    if (tid < VQ_K) C[tid] = cb[tid];
    if (tid < NW)   H[tid] = 0u;
    __syncthreads();

    // Stable rank-sort into S[1..64] (wave 0 only; C[j] reads broadcast).
    if (tid < VQ_K) {
        const float c = C[tid];
        int rank = 0;
#pragma unroll
        for (int j = 0; j < VQ_K; ++j) {
            const float cj = C[j];
            rank += (cj < c || (cj == c && j < tid)) ? 1 : 0;
        }
        S[rank + 1] = c;
    }
    if (tid == 0) S[0] = INF;
    if (tid >= VQ_K + 1 && tid <= VQ_K + 3) S[tid] = INF;
    __syncthreads();

    const float lo  = S[1];
    const float hi  = S[VQ_K];
    const float inv = (hi > lo) ? ((float)NB / (hi - lo)) : 0.0f;
    const float nlo = -lo * inv;      // same value in every thread/block

    if (tid < VQ_K) {
        const int k = vq_key(S[tid + 1], inv, nlo);
        atomicAdd(&H[k >> 2], 1u << ((k & 3) * 8));
    }
    __syncthreads();

    // Wave 0: exclusive scan over 256 words (4 words/lane + shfl scan).
    if (tid < 64) {
        const unsigned w0 = H[4 * tid], w1 = H[4 * tid + 1];
        const unsigned w2 = H[4 * tid + 2], w3 = H[4 * tid + 3];
        const int s0 = (int)bytesum(w0), s1 = (int)bytesum(w1);
        const int s2 = (int)bytesum(w2), s3 = (int)bytesum(w3);
        const int tot = s0 + s1 + s2 + s3;
        int acc = tot;
#pragma unroll
        for (int d = 1; d < 64; d <<= 1) {
            int u = __shfl_up(acc, d, 64);
            if (tid >= d) acc += u;
        }
        const int base = acc - tot;
        Hs[4 * tid]     = (unsigned)base;
        Hs[4 * tid + 1] = (unsigned)(base + s0);
        Hs[4 * tid + 2] = (unsigned)(base + s0 + s1);
        Hs[4 * tid + 3] = (unsigned)(base + s0 + s1 + s2);
    }
    __syncthreads();

    // Fill T: one bucket per thread (NB == TPB); lane-consecutive b128 writes.
    {
        const int b = tid;
        const unsigned hw = H[b >> 2];
        const int sh = (b & 3) * 8;
        const int h = (int)((hw >> sh) & 0xFFu);
        const unsigned below = hw & ((sh == 0) ? 0u : ((1u << sh) - 1u));
        const int p0 = (int)Hs[b >> 2] + (int)bytesum(below);
        float4 ent;
        if (h >= 3) ent = make_float4(NANF, NANF, NANF, NANF);
        else        ent = make_float4(S[p0], S[p0 + 1], S[p0 + 2], S[p0 + 3]);
        T[b] = ent;
    }
    __syncthreads();

    // ---- stream SEG float4 per thread ----
    const int base4 = blockIdx.x * BLK_F4 + tid;   // launcher sends full blocks
    const float4* in4 = reinterpret_cast<const float4*>(w);
    float4* out4 = reinterpret_cast<float4*>(out);

    float4 x[SEG];
#pragma unroll
    for (int s = 0; s < SEG; ++s) x[s] = in4[base4 + s * TPB];

#pragma unroll
    for (int s = 0; s < SEG; ++s) {
        float ex[4] = {x[s].x, x[s].y, x[s].z, x[s].w};
        float r[4];
#pragma unroll
        for (int j = 0; j < 4; ++j) {
            const float wv = ex[j];
            const int k = vq_key(wv, inv, nlo);
            const float4 ent = T[k];              // one ds_read_b128
            const bool s1 = (ent.y <= wv);
            const bool s2 = (ent.z <= wv);
            const float cl = s2 ? ent.z : (s1 ? ent.y : ent.x);
            const float cr = s2 ? ent.w : (s1 ? ent.z : ent.y);
            const float dl = wv - cl, dr = wv - cr;
            const float dl2 = dl * dl, dr2 = dr * dr;
            const bool rlt = (dr2 < dl2);
            float q = rlt ? cr : cl;
            // NaN-safe tie/degenerate guard: neither strictly smaller.
            const bool bad = !rlt && !(dl2 < dr2) && (cl != cr);
            if (__any(bad)) {                     // uniform, ~never taken
                if (bad) {
                    float c0 = C[0], d0 = wv - c0;
                    float bd = d0 * d0, bv = c0;
#pragma unroll 1
                    for (int kk = 1; kk < VQ_K; ++kk) {
                        float cc = C[kk], d = wv - cc, dd = d * d;
                        bool lt = dd < bd;
                        bd = lt ? dd : bd;
                        bv = lt ? cc : bv;
                    }
                    q = bv;
                }
            }
            r[j] = q;
        }
        out4[base4 + s * TPB] = make_float4(r[0], r[1], r[2], r[3]);
    }
}

// Naive exact fallback for any remainder elements.
__global__ void vq_tail_kernel(const float* __restrict__ w,
                               const float* __restrict__ cb,
                               float* __restrict__ out, int start, int n) {
    int i = start + blockIdx.x * blockDim.x + threadIdx.x;
    if (i >= n) return;
    float wx = w[i];
    float c0 = cb[0], d0 = wx - c0;
    float bd = d0 * d0, bv = c0;
#pragma unroll
    for (int k = 1; k < VQ_K; ++k) {
        float c = cb[k], d = wx - c, dd = d * d;
        bool lt = dd < bd;
        bd = lt ? dd : bd;
        bv = lt ? c : bv;
    }
    out[i] = bv;
}

extern "C" void kernel_launch(void* const* d_in, const int* in_sizes, int n_in,
                              void* d_out, int out_size, void* d_ws, size_t ws_size,
                              hipStream_t stream) {
    const float* w  = (const float*)d_in[0];
    const float* cb = (const float*)d_in[1];
    float* out = (float*)d_out;
    const int n  = in_sizes[0];
    const int n4 = n / 4;

    const int grid = n4 / BLK_F4;                 // full blocks only
    if (grid > 0) {
        vq_kernel<<<grid, TPB, 0, stream>>>(w, cb, out, n4);
    }
    const int done = grid * BLK_F4 * 4;
    if (done < n) {
        const int rem = n - done;
        vq_tail_kernel<<<(rem + TPB - 1) / TPB, TPB, 0, stream>>>(w, cb, out, done, n);
    }
}